// Round 3
// baseline (82.741 us; speedup 1.0000x reference)
//
#include <hip/hip_runtime.h>
#include <hip/hip_fp16.h>

#define BATCH   512
#define IN_DIM  16384
#define KNN     32

typedef __attribute__((ext_vector_type(4))) _Float16 half4v;
typedef __attribute__((ext_vector_type(2))) _Float16 half2v;

// ---------------------------------------------------------------------------
// Transpose x (BATCH, IN_DIM) fp32 -> xt (IN_DIM, BATCH) fp16.
// ---------------------------------------------------------------------------
__global__ __launch_bounds__(256) void transpose_h(const float* __restrict__ in,
                                                   _Float16* __restrict__ out) {
    __shared__ float tile[32][33];
    const int bx = blockIdx.x * 32;          // IN_DIM base
    const int by = blockIdx.y * 32;          // BATCH base
    const int tx = threadIdx.x & 31;
    const int ty = threadIdx.x >> 5;         // 0..7
#pragma unroll
    for (int j = 0; j < 32; j += 8)
        tile[ty + j][tx] = in[(size_t)(by + ty + j) * IN_DIM + bx + tx];
    __syncthreads();
    const int r = threadIdx.x >> 3;          // 0..31  (local d)
    const int c = (threadIdx.x & 7) * 4;     // local batch base
    half4v h;
    h[0] = (_Float16)tile[c + 0][r];
    h[1] = (_Float16)tile[c + 1][r];
    h[2] = (_Float16)tile[c + 2][r];
    h[3] = (_Float16)tile[c + 3][r];
    *(half4v*)(out + (size_t)(bx + r) * BATCH + by + c) = h;
}

// ---------------------------------------------------------------------------
// Layer kernel, scalar-half gathers, CHUNK=64, NCHUNK=8 (layer 0).
// Wave = 64 lanes = one batch chunk; DPER output features per wave.
// chunk = bid&7 pins each chunk's 2 MB input slab to one XCD's L2.
// ---------------------------------------------------------------------------
template<int DPER>
__global__ __launch_bounds__(64) void lcn_h1(const _Float16* __restrict__ xt,
                                             const float* __restrict__ w,
                                             const float* __restrict__ bias,
                                             const int* __restrict__ knn,
                                             _Float16* __restrict__ yt) {
    const int dg = blockIdx.x >> 3;
    const int b  = (blockIdx.x & 7) * 64 + threadIdx.x;
    const _Float16* xb = xt + b;
    const int*   kp = knn + (size_t)dg * DPER * KNN;
    const float* wp = w   + (size_t)dg * DPER * KNN;
    float acc[DPER];
#pragma unroll
    for (int j = 0; j < DPER; ++j) acc[j] = 0.f;
#pragma unroll 4
    for (int k = 0; k < KNN; ++k) {
#pragma unroll
        for (int j = 0; j < DPER; ++j) {
            const int   idx = kp[j * KNN + k];     // scalar
            const float wv  = wp[j * KNN + k];     // scalar
            acc[j] += wv * (float)xb[(size_t)idx * BATCH];
        }
    }
#pragma unroll
    for (int j = 0; j < DPER; ++j) {
        const int d = dg * DPER + j;
        yt[(size_t)d * BATCH + b] = (_Float16)fmaxf(acc[j] + bias[d], 0.f);
    }
}

// ---------------------------------------------------------------------------
// Layer kernel, half2 gathers, CHUNK=128, NCHUNK=4 (layers 1,2).
// chunk = bid&3; XCD x (= bid&7) sees only chunk x&3 -> slab <= 2 MB in L2.
// ---------------------------------------------------------------------------
template<int DPER>
__global__ __launch_bounds__(64) void lcn_h2(const _Float16* __restrict__ xt,
                                             const float* __restrict__ w,
                                             const float* __restrict__ bias,
                                             const int* __restrict__ knn,
                                             _Float16* __restrict__ yt) {
    const int dg = blockIdx.x >> 2;
    const int b  = (blockIdx.x & 3) * 128 + 2 * threadIdx.x;
    const _Float16* xb = xt + b;
    const int*   kp = knn + (size_t)dg * DPER * KNN;
    const float* wp = w   + (size_t)dg * DPER * KNN;
    float ax[DPER], ay[DPER];
#pragma unroll
    for (int j = 0; j < DPER; ++j) { ax[j] = 0.f; ay[j] = 0.f; }
#pragma unroll 4
    for (int k = 0; k < KNN; ++k) {
#pragma unroll
        for (int j = 0; j < DPER; ++j) {
            const int   idx = kp[j * KNN + k];     // scalar
            const float wv  = wp[j * KNN + k];     // scalar
            const half2v v  = *(const half2v*)(xb + (size_t)idx * BATCH);
            ax[j] += wv * (float)v[0];
            ay[j] += wv * (float)v[1];
        }
    }
#pragma unroll
    for (int j = 0; j < DPER; ++j) {
        const int d = dg * DPER + j;
        const float bv = bias[d];
        half2v r;
        r[0] = (_Float16)fmaxf(ax[j] + bv, 0.f);
        r[1] = (_Float16)fmaxf(ay[j] + bv, 0.f);
        *(half2v*)(yt + (size_t)d * BATCH + b) = r;
    }
}

// ---------------------------------------------------------------------------
// FC stage 1: partial sums over d-chunks of 256.
// ---------------------------------------------------------------------------
__global__ __launch_bounds__(256) void fc_partial(const _Float16* __restrict__ y2t,
                                                  const float* __restrict__ fcw,
                                                  float* __restrict__ part) {
    const int o  = blockIdx.x & 15;
    const int bh = (blockIdx.x >> 4) & 1;
    const int ch = blockIdx.x >> 5;          // 0..7
    const int b  = bh * 256 + threadIdx.x;
    const int d0 = ch * 256;
    float a0 = 0.f, a1 = 0.f, a2 = 0.f, a3 = 0.f;
#pragma unroll 4
    for (int d = d0; d < d0 + 256; d += 4) {
        a0 += (float)y2t[(size_t)(d + 0) * BATCH + b] * fcw[(d + 0) * 16 + o];
        a1 += (float)y2t[(size_t)(d + 1) * BATCH + b] * fcw[(d + 1) * 16 + o];
        a2 += (float)y2t[(size_t)(d + 2) * BATCH + b] * fcw[(d + 2) * 16 + o];
        a3 += (float)y2t[(size_t)(d + 3) * BATCH + b] * fcw[(d + 3) * 16 + o];
    }
    part[((size_t)b * 16 + o) * 8 + ch] = (a0 + a1) + (a2 + a3);
}

__global__ __launch_bounds__(256) void fc_final(const float* __restrict__ part,
                                                const float* __restrict__ fcb,
                                                float* __restrict__ out) {
    const int t = blockIdx.x * 256 + threadIdx.x;       // 0..8191
    const float4 p0 = *(const float4*)(part + (size_t)t * 8);
    const float4 p1 = *(const float4*)(part + (size_t)t * 8 + 4);
    out[t] = ((p0.x + p0.y) + (p0.z + p0.w)) + ((p1.x + p1.y) + (p1.z + p1.w))
             + fcb[t & 15];
}

extern "C" void kernel_launch(void* const* d_in, const int* in_sizes, int n_in,
                              void* d_out, int out_size, void* d_ws, size_t ws_size,
                              hipStream_t stream) {
    // setup_inputs() order: x, w0,b0,knn0, w1,b1,knn1, w2,b2,knn2, fc_w, fc_b
    const float* x    = (const float*)d_in[0];
    const float* w0   = (const float*)d_in[1];
    const float* b0   = (const float*)d_in[2];
    const int*   knn0 = (const int*)  d_in[3];
    const float* w1   = (const float*)d_in[4];
    const float* b1   = (const float*)d_in[5];
    const int*   knn1 = (const int*)  d_in[6];
    const float* w2   = (const float*)d_in[7];
    const float* b2   = (const float*)d_in[8];
    const int*   knn2 = (const int*)  d_in[9];
    const float* fcw  = (const float*)d_in[10];
    const float* fcb  = (const float*)d_in[11];
    float* out = (float*)d_out;

    // Workspace (fp16 intermediates, non-overlapping, 30.25 MB total):
    //   xt   @  0 MB : 16 MB    y0t @ 16 MB : 8 MB
    //   y1t  @ 24 MB :  4 MB    y2t @ 28 MB : 2 MB    part @ 30 MB : 256 KB
    char* ws = (char*)d_ws;
    _Float16* xt   = (_Float16*)(ws);
    _Float16* y0t  = (_Float16*)(ws + ((size_t)16 << 20));
    _Float16* y1t  = (_Float16*)(ws + ((size_t)24 << 20));
    _Float16* y2t  = (_Float16*)(ws + ((size_t)28 << 20));
    float*    part = (float*)   (ws + ((size_t)30 << 20));

    transpose_h<<<dim3(IN_DIM / 32, BATCH / 32), 256, 0, stream>>>(x, xt);
    // L0: 8192 d / 8 per wave * 8 chunks = 8192 blocks (32 waves/CU)
    lcn_h1<8><<<(8192 / 8) * 8, 64, 0, stream>>>(xt,  w0, b0, knn0, y0t);
    // L1: 4096 d / 4 per wave * 4 chunks = 4096 blocks
    lcn_h2<4><<<(4096 / 4) * 4, 64, 0, stream>>>(y0t, w1, b1, knn1, y1t);
    // L2: 2048 d / 4 per wave * 4 chunks = 2048 blocks
    lcn_h2<4><<<(2048 / 4) * 4, 64, 0, stream>>>(y1t, w2, b2, knn2, y2t);
    fc_partial<<<256, 256, 0, stream>>>(y2t, fcw, part);
    fc_final<<<32, 256, 0, stream>>>(part, fcb, out);
}